// Round 2
// baseline (346.128 us; speedup 1.0000x reference)
//
#include <hip/hip_runtime.h>
#include <cstdint>
#include <math.h>

// ---------------------------------------------------------------------------
// AttentionBlock: GroupNorm(32) -> 1x1 conv QKV -> MHA(8 heads, hd=64)
//                 -> 1x1 conv proj -> +residual.   B=16, C=512, N=H*W=1024.
// I/O tensors are FP32 (reference is jnp.float32). Internal math: bf16 MFMA.
//
// ws layout (byte offsets):
//   0        float2 stats[512]          (mean, rstd) per (b, group)
//   64K      qwb  bf16[1536*512]        qkv_w converted to bf16
//   2M       pwb  bf16[512*512]         proj_w converted to bf16
//   4M       hnt  (B, N, C)   bf16      groupnormed x, (n, c); REUSED as ont
//   20M      qkt  (B, N, 1024) bf16     cols [0,512)=q, [512,1024)=k
//   52M      vt   (B, 512, N) bf16      v channel-major (d, n)
// ---------------------------------------------------------------------------

typedef __bf16 bf16;
typedef __attribute__((ext_vector_type(8))) __bf16 bf16x8;
typedef __attribute__((ext_vector_type(4))) float f32x4;

union U8 { uint4 u4; bf16x8 v; bf16 h[8]; };
union U4 { ushort4 u; bf16 h[4]; };
union F4 { float4 v; float f[4]; };

typedef __attribute__((address_space(1))) void* gp1;
typedef __attribute__((address_space(3))) void* lp3;

// async global->LDS, 16B/lane. LDS dest = wave-uniform base + lane*16.
__device__ __forceinline__ void async16(const void* g, void* l) {
  __builtin_amdgcn_global_load_lds((gp1)g, (lp3)l, 16, 0, 0);
}

// ---------------------------------------------------------------------------
// Kernel 0: convert fp32 weights to bf16. qw: 1536x512, pw: 512x512.
// ---------------------------------------------------------------------------
__global__ __launch_bounds__(256) void cvt_w(const float* __restrict__ qw,
                                             const float* __restrict__ pw,
                                             bf16* __restrict__ qwb,
                                             bf16* __restrict__ pwb) {
  int i = blockIdx.x * 256 + threadIdx.x;     // float4 index; 262144 total
  F4 v; bf16* dst;
  if (i < 196608) { v.v = ((const float4*)qw)[i]; dst = qwb + (size_t)i * 4; }
  else { v.v = ((const float4*)pw)[i - 196608]; dst = pwb + (size_t)(i - 196608) * 4; }
  U4 o;
#pragma unroll
  for (int j = 0; j < 4; j++) o.h[j] = (bf16)v.f[j];
  *(ushort4*)dst = o.u;
}

// ---------------------------------------------------------------------------
// Kernel 1: per-(b,group) mean/rstd. One block per (b,g): 16ch x 1024 fp32.
// ---------------------------------------------------------------------------
__global__ __launch_bounds__(256) void gn_stats(const float* __restrict__ x,
                                                float2* __restrict__ stats) {
  int bg = blockIdx.x;                         // b*32 + g
  const float* base = x + (size_t)bg * 16384;
  int t = threadIdx.x;
  float s = 0.f, ss = 0.f;
#pragma unroll
  for (int p = 0; p < 16; p++) {
    F4 u; u.v = *(const float4*)(base + (size_t)(p * 256 + t) * 4);
#pragma unroll
    for (int i = 0; i < 4; i++) { float v = u.f[i]; s += v; ss += v * v; }
  }
  for (int off = 1; off < 64; off <<= 1) { s += __shfl_xor(s, off); ss += __shfl_xor(ss, off); }
  __shared__ float red[8];
  int w = t >> 6;
  if ((t & 63) == 0) { red[w] = s; red[4 + w] = ss; }
  __syncthreads();
  if (t == 0) {
    float S = red[0] + red[1] + red[2] + red[3];
    float SS = red[4] + red[5] + red[6] + red[7];
    float mean = S * (1.f / 16384.f);
    float var = SS * (1.f / 16384.f) - mean * mean;
    stats[bg] = make_float2(mean, rsqrtf(var + 1e-5f));
  }
}

// ---------------------------------------------------------------------------
// Kernel 2: hn_t[b][n][c] = bf16((x[b][c][n]-mean)*rstd*w + bias), transposed.
// Per lane: 8c x 4n micro-tile. Loads: 8-lane groups cover 128B contiguous n;
// stores: 8-lane groups cover 128B contiguous c. Grid (ct=4, nt=16, b=16).
// ---------------------------------------------------------------------------
__global__ __launch_bounds__(256) void gn_apply(const float* __restrict__ x,
                                                const float* __restrict__ nwp,
                                                const float* __restrict__ nbp,
                                                const float2* __restrict__ stats,
                                                bf16* __restrict__ hnt) {
  int b = blockIdx.z, nt = blockIdx.y, ct = blockIdx.x;
  int t = threadIdx.x, w = t >> 6, l = t & 63;
  int wc = w & 1, wn = w >> 1;
  int cb = ct * 128 + wc * 64 + (l & 7) * 8;   // 8 channels per lane
  int n0 = nt * 64 + wn * 32 + (l >> 3) * 4;   // 4 n per lane
  float2 ms = stats[b * 32 + (cb >> 4)];       // cb..cb+7 in one 16-ch group
  float wgt[8], bia[8];
#pragma unroll
  for (int i = 0; i < 8; i++) {
    float wi = nwp[cb + i] * ms.y;
    wgt[i] = wi;
    bia[i] = nbp[cb + i] - ms.x * wi;
  }
  F4 in[8];
  const float* xb = x + ((size_t)b * 512 + cb) * 1024 + n0;
#pragma unroll
  for (int i = 0; i < 8; i++) in[i].v = *(const float4*)(xb + (size_t)i * 1024);
  bf16* ob = hnt + ((size_t)b * 1024 + n0) * 512 + cb;
#pragma unroll
  for (int j = 0; j < 4; j++) {
    U8 o;
#pragma unroll
    for (int i = 0; i < 8; i++) o.h[i] = (bf16)(in[i].f[j] * wgt[i] + bia[i]);
    *(uint4*)(ob + (size_t)j * 512) = o.u4;
  }
}

// ---------------------------------------------------------------------------
// Shared gemm-BT core (m97 recipe): C[128n x 128o] = A(128x512) * B(128x512)^T
// A rows: ga0 (+row*512), B rows: gb0 (+row*512); both bf16. BK=32,
// global_load_lds width 16, 4 waves -> 64x64 quadrants, 4x4 16x16x32 frags.
// ---------------------------------------------------------------------------
__device__ __forceinline__ void gemm_bt_core(const bf16* ga0, const bf16* gb0,
                                             bf16* At, bf16* Bt,
                                             f32x4 (&acc)[4][4], int w, int l) {
  const bf16* ga = ga0 + (size_t)(w * 16 + (l >> 2)) * 512 + (l & 3) * 8;
  const bf16* gb = gb0 + (size_t)(w * 16 + (l >> 2)) * 512 + (l & 3) * 8;
  int wr = w >> 1, wc = w & 1;
  const bf16* Ab = At + (wr * 64 + (l & 15)) * 32 + (l >> 4) * 8;
  const bf16* Bb = Bt + (wc * 64 + (l & 15)) * 32 + (l >> 4) * 8;
  bf16* lA = At + w * 16 * 32;   // wave-uniform LDS staging base
  bf16* lB = Bt + w * 16 * 32;
  for (int k0 = 0; k0 < 512; k0 += 32) {
    async16(ga + k0, lA);
    async16(ga + 64 * 512 + k0, lA + 64 * 32);
    async16(gb + k0, lB);
    async16(gb + 64 * 512 + k0, lB + 64 * 32);
    __syncthreads();
    bf16x8 af[4], bfr[4];
#pragma unroll
    for (int i = 0; i < 4; i++) {
      af[i] = *(const bf16x8*)(Ab + i * 512);   // +16 rows * 32
      bfr[i] = *(const bf16x8*)(Bb + i * 512);
    }
#pragma unroll
    for (int i = 0; i < 4; i++)
#pragma unroll
      for (int j = 0; j < 4; j++)
        acc[i][j] = __builtin_amdgcn_mfma_f32_16x16x32_bf16(af[i], bfr[j], acc[i][j], 0, 0, 0);
    __syncthreads();
  }
}

// ---------------------------------------------------------------------------
// Kernel 3: qkv[b][n][o] = sum_c hn_t[b][n][c]*qkv_w[o][c] + qkv_b[o].
// o-tiles 0..7 -> qk_t (row-major (n,o)); 8..11 -> v_t transposed (d, n).
// Grid (ot=12, nt=8, b=16).
// ---------------------------------------------------------------------------
__global__ __launch_bounds__(256, 2) void qkv_gemm(const bf16* __restrict__ hnt,
                                                   const bf16* __restrict__ qwb,
                                                   const float* __restrict__ qb,
                                                   bf16* __restrict__ qkt,
                                                   bf16* __restrict__ vt) {
  __shared__ bf16 At[128 * 32];
  __shared__ bf16 Bt[128 * 32];
  int b = blockIdx.z, mt = blockIdx.y, ot = blockIdx.x;
  int m0 = mt * 128, o0 = ot * 128;
  int t = threadIdx.x, w = t >> 6, l = t & 63;
  f32x4 acc[4][4] = {};
  gemm_bt_core(hnt + ((size_t)b * 1024 + m0) * 512, qwb + (size_t)o0 * 512, At, Bt, acc, w, l);

  int wr = w >> 1, wc = w & 1, quad = l >> 4, li = l & 15;
#pragma unroll
  for (int i = 0; i < 4; i++) {
    int gn = m0 + wr * 64 + i * 16 + quad * 4;
#pragma unroll
    for (int j = 0; j < 4; j++) {
      int go = o0 + wc * 64 + j * 16 + li;
      float bias = qb[go];
      if (ot < 8) {             // q,k region: (n, o) layout, scalar 2B stores
        bf16* p = qkt + ((size_t)b * 1024 + gn) * 1024 + go;
#pragma unroll
        for (int r = 0; r < 4; r++) p[(size_t)r * 1024] = (bf16)(acc[i][j][r] + bias);
      } else {                  // v region: transposed (d, n), packed 8B stores
        U4 pk;
#pragma unroll
        for (int r = 0; r < 4; r++) pk.h[r] = (bf16)(acc[i][j][r] + bias);
        *(ushort4*)(vt + ((size_t)b * 512 + (go - 1024)) * 1024 + gn) = pk.u;
      }
    }
  }
}

// ---------------------------------------------------------------------------
// Kernel 4: flash attention. Block = (b, h, 128 q-rows); 4 waves x 32 rows.
// K/V fragments read directly from global (L2-resident). No barriers:
// P C->A layout transform through per-wave private LDS.
// ---------------------------------------------------------------------------
__global__ __launch_bounds__(256, 2) void attn(const bf16* __restrict__ qkt,
                                               const bf16* __restrict__ vt,
                                               bf16* __restrict__ ont) {
  __shared__ bf16 plds[4][32 * 136];   // per-wave P tile, padded stride 136
  int b = blockIdx.z, h = blockIdx.y, qt = blockIdx.x;
  int t = threadIdx.x, w = t >> 6, l = t & 63;
  int quad = l >> 4, li = l & 15;
  int q0 = qt * 128 + w * 32;

  const bf16* qb = qkt + (size_t)b * 1024 * 1024 + h * 64;
  const bf16* kb = qkt + (size_t)b * 1024 * 1024 + 512 + h * 64;
  const bf16* vb = vt + ((size_t)b * 512 + h * 64) * 1024;

  // Q fragments (A layout), scale 1/8 folded in (exact in bf16).
  bf16x8 qa[2][2];
#pragma unroll
  for (int rf = 0; rf < 2; rf++)
#pragma unroll
    for (int ks = 0; ks < 2; ks++) {
      U8 u;
      u.u4 = *(const uint4*)(qb + (size_t)(q0 + rf * 16 + li) * 1024 + ks * 32 + quad * 8);
#pragma unroll
      for (int i = 0; i < 8; i++) u.h[i] = (bf16)((float)u.h[i] * 0.125f);
      qa[rf][ks] = u.v;
    }

  float mrun[2][4], lrun[2][4];
  f32x4 of[2][4] = {};
#pragma unroll
  for (int rf = 0; rf < 2; rf++)
#pragma unroll
    for (int r = 0; r < 4; r++) { mrun[rf][r] = -INFINITY; lrun[rf][r] = 0.f; }

  bf16* pl = plds[w];
  for (int m0 = 0; m0 < 1024; m0 += 128) {
    // ---- S = Q K^T (scaled) ----
    f32x4 s[2][8] = {};
#pragma unroll
    for (int cf = 0; cf < 8; cf++)
#pragma unroll
      for (int ks = 0; ks < 2; ks++) {
        U8 u;
        u.u4 = *(const uint4*)(kb + (size_t)(m0 + cf * 16 + li) * 1024 + ks * 32 + quad * 8);
#pragma unroll
        for (int rf = 0; rf < 2; rf++)
          s[rf][cf] = __builtin_amdgcn_mfma_f32_16x16x32_bf16(qa[rf][ks], u.v, s[rf][cf], 0, 0, 0);
      }
    // ---- online softmax (rows live on 16-lane groups) ----
#pragma unroll
    for (int rf = 0; rf < 2; rf++) {
#pragma unroll
      for (int r = 0; r < 4; r++) {
        float v = s[rf][0][r];
#pragma unroll
        for (int cf = 1; cf < 8; cf++) v = fmaxf(v, s[rf][cf][r]);
        for (int off = 1; off < 16; off <<= 1) v = fmaxf(v, __shfl_xor(v, off));
        float mnew = fmaxf(mrun[rf][r], v);
        float alpha = exp2f((mrun[rf][r] - mnew) * 1.44269504f);
        mrun[rf][r] = mnew;
        float rs = 0.f;
#pragma unroll
        for (int cf = 0; cf < 8; cf++) {
          float e = exp2f((s[rf][cf][r] - mnew) * 1.44269504f);
          s[rf][cf][r] = e; rs += e;
        }
        for (int off = 1; off < 16; off <<= 1) rs += __shfl_xor(rs, off);
        lrun[rf][r] = lrun[rf][r] * alpha + rs;
#pragma unroll
        for (int df = 0; df < 4; df++) of[rf][df][r] *= alpha;
      }
    }
    // ---- P: C-layout -> A-layout via per-wave private LDS ----
#pragma unroll
    for (int rf = 0; rf < 2; rf++)
#pragma unroll
      for (int cf = 0; cf < 8; cf++)
#pragma unroll
        for (int r = 0; r < 4; r++)
          pl[(rf * 16 + quad * 4 + r) * 136 + cf * 16 + li] = (bf16)s[rf][cf][r];
    // ---- O += P V ----
#pragma unroll
    for (int ms = 0; ms < 4; ms++) {
      bf16x8 pa[2];
#pragma unroll
      for (int rf = 0; rf < 2; rf++)
        pa[rf] = *(const bf16x8*)(pl + (rf * 16 + li) * 136 + ms * 32 + quad * 8);
#pragma unroll
      for (int df = 0; df < 4; df++) {
        U8 u;
        u.u4 = *(const uint4*)(vb + (size_t)(df * 16 + li) * 1024 + m0 + ms * 32 + quad * 8);
#pragma unroll
        for (int rf = 0; rf < 2; rf++)
          of[rf][df] = __builtin_amdgcn_mfma_f32_16x16x32_bf16(pa[rf], u.v, of[rf][df], 0, 0, 0);
      }
    }
  }
  // ---- epilogue: O /= l, store o_nt (n, c) ----
  bf16* ob = ont + (size_t)b * 1024 * 512 + h * 64;
#pragma unroll
  for (int rf = 0; rf < 2; rf++) {
    float inv[4];
#pragma unroll
    for (int r = 0; r < 4; r++) inv[r] = 1.f / lrun[rf][r];
#pragma unroll
    for (int df = 0; df < 4; df++)
#pragma unroll
      for (int r = 0; r < 4; r++)
        ob[(size_t)(q0 + rf * 16 + quad * 4 + r) * 512 + df * 16 + li] =
            (bf16)(of[rf][df][r] * inv[r]);
  }
}

// ---------------------------------------------------------------------------
// Kernel 5: out[b][o][n] = sum_c o_nt[b][n][c]*proj_w[o][c] + proj_b[o] + x.
// gemm-BT; epilogue adds fp32 residual, fp32 float4 stores. Grid (4, 8, 16).
// ---------------------------------------------------------------------------
__global__ __launch_bounds__(256, 2) void proj_gemm(const bf16* __restrict__ ont,
                                                    const bf16* __restrict__ pwb,
                                                    const float* __restrict__ pb,
                                                    const float* __restrict__ x,
                                                    float* __restrict__ out) {
  __shared__ bf16 At[128 * 32];
  __shared__ bf16 Bt[128 * 32];
  int b = blockIdx.z, mt = blockIdx.y, ot = blockIdx.x;
  int m0 = mt * 128, o0 = ot * 128;
  int t = threadIdx.x, w = t >> 6, l = t & 63;
  f32x4 acc[4][4] = {};
  gemm_bt_core(ont + ((size_t)b * 1024 + m0) * 512, pwb + (size_t)o0 * 512, At, Bt, acc, w, l);

  int wr = w >> 1, wc = w & 1, quad = l >> 4, li = l & 15;
#pragma unroll
  for (int i = 0; i < 4; i++) {
    int gn = m0 + wr * 64 + i * 16 + quad * 4;
#pragma unroll
    for (int j = 0; j < 4; j++) {
      int go = o0 + wc * 64 + j * 16 + li;
      float bias = pb[go];
      F4 xres; xres.v = *(const float4*)(x + ((size_t)b * 512 + go) * 1024 + gn);
      F4 o;
#pragma unroll
      for (int r = 0; r < 4; r++) o.f[r] = acc[i][j][r] + bias + xres.f[r];
      *(float4*)(out + ((size_t)b * 512 + go) * 1024 + gn) = o.v;
    }
  }
}

// ---------------------------------------------------------------------------
extern "C" void kernel_launch(void* const* d_in, const int* in_sizes, int n_in,
                              void* d_out, int out_size, void* d_ws, size_t ws_size,
                              hipStream_t stream) {
  const float* x  = (const float*)d_in[0];
  const float* nw = (const float*)d_in[1];
  const float* nb = (const float*)d_in[2];
  const float* qw = (const float*)d_in[3];
  const float* qb = (const float*)d_in[4];
  const float* pw = (const float*)d_in[5];
  const float* pb = (const float*)d_in[6];
  float* out = (float*)d_out;

  char* ws = (char*)d_ws;
  float2* stats = (float2*)ws;
  bf16* qwb = (bf16*)(ws + (64u << 10));
  bf16* pwb = (bf16*)(ws + (2u << 20));
  bf16* hnt = (bf16*)(ws + (4u << 20));   // 16MB; reused as ont after qkv_gemm
  bf16* qkt = (bf16*)(ws + (20u << 20));  // 32MB
  bf16* vt  = (bf16*)(ws + (52u << 20));  // 16MB
  bf16* ont = hnt;

  cvt_w<<<1024, 256, 0, stream>>>(qw, pw, qwb, pwb);
  gn_stats<<<512, 256, 0, stream>>>(x, stats);
  gn_apply<<<dim3(4, 16, 16), 256, 0, stream>>>(x, nw, nb, stats, hnt);
  qkv_gemm<<<dim3(12, 8, 16), 256, 0, stream>>>(hnt, qwb, qb, qkt, vt);
  attn<<<dim3(8, 8, 16), 256, 0, stream>>>(qkt, vt, ont);
  proj_gemm<<<dim3(4, 8, 16), 256, 0, stream>>>(ont, pwb, pb, x, out);
}

// Round 3
// 332.568 us; speedup vs baseline: 1.0408x; 1.0408x over previous
//
#include <hip/hip_runtime.h>
#include <cstdint>
#include <math.h>

// ---------------------------------------------------------------------------
// AttentionBlock: GroupNorm(32) -> 1x1 conv QKV -> MHA(8 heads, hd=64)
//                 -> 1x1 conv proj -> +residual.   B=16, C=512, N=H*W=1024.
// I/O tensors are FP32. Internal math: bf16 MFMA.
//
// ws layout (byte offsets):
//   0        float2 stats[512]          (mean, rstd) per (b, group)
//   64K      qwb  bf16[1536*512]        qkv_w converted to bf16
//   2M       pwb  bf16[512*512]         proj_w converted to bf16
//   4M       hnt  (B, N, C)   bf16      groupnormed x, (n, c); REUSED as ont
//   20M      qkt  (B, N, 1024) bf16     cols [0,512)=q, [512,1024)=k
//   52M      vt   (B, 512, N) bf16      v channel-major (d, n)
// ---------------------------------------------------------------------------

typedef __bf16 bf16;
typedef __attribute__((ext_vector_type(8))) __bf16 bf16x8;
typedef __attribute__((ext_vector_type(4))) float f32x4;

union U8 { uint4 u4; bf16x8 v; bf16 h[8]; };
union U4 { ushort4 u; bf16 h[4]; };
union F4 { float4 v; float f[4]; };

typedef __attribute__((address_space(1))) void* gp1;
typedef __attribute__((address_space(3))) void* lp3;

__device__ __forceinline__ void async16(const void* g, void* l) {
  __builtin_amdgcn_global_load_lds((gp1)g, (lp3)l, 16, 0, 0);
}

#define LOG2E 1.44269504f

// ---------------------------------------------------------------------------
// Kernel 0: convert fp32 weights to bf16. qw: 1536x512, pw: 512x512.
// ---------------------------------------------------------------------------
__global__ __launch_bounds__(256) void cvt_w(const float* __restrict__ qw,
                                             const float* __restrict__ pw,
                                             bf16* __restrict__ qwb,
                                             bf16* __restrict__ pwb) {
  int i = blockIdx.x * 256 + threadIdx.x;     // float4 index; 262144 total
  F4 v; bf16* dst;
  if (i < 196608) { v.v = ((const float4*)qw)[i]; dst = qwb + (size_t)i * 4; }
  else { v.v = ((const float4*)pw)[i - 196608]; dst = pwb + (size_t)(i - 196608) * 4; }
  U4 o;
#pragma unroll
  for (int j = 0; j < 4; j++) o.h[j] = (bf16)v.f[j];
  *(ushort4*)dst = o.u;
}

// ---------------------------------------------------------------------------
// Kernel 1: per-(b,group) mean/rstd. One block per (b,g): 16ch x 1024 fp32.
// ---------------------------------------------------------------------------
__global__ __launch_bounds__(256) void gn_stats(const float* __restrict__ x,
                                                float2* __restrict__ stats) {
  int bg = blockIdx.x;                         // b*32 + g
  const float* base = x + (size_t)bg * 16384;
  int t = threadIdx.x;
  float s = 0.f, ss = 0.f;
#pragma unroll
  for (int p = 0; p < 16; p++) {
    F4 u; u.v = *(const float4*)(base + (size_t)(p * 256 + t) * 4);
#pragma unroll
    for (int i = 0; i < 4; i++) { float v = u.f[i]; s += v; ss += v * v; }
  }
  for (int off = 1; off < 64; off <<= 1) { s += __shfl_xor(s, off); ss += __shfl_xor(ss, off); }
  __shared__ float red[8];
  int w = t >> 6;
  if ((t & 63) == 0) { red[w] = s; red[4 + w] = ss; }
  __syncthreads();
  if (t == 0) {
    float S = red[0] + red[1] + red[2] + red[3];
    float SS = red[4] + red[5] + red[6] + red[7];
    float mean = S * (1.f / 16384.f);
    float var = SS * (1.f / 16384.f) - mean * mean;
    stats[bg] = make_float2(mean, rsqrtf(var + 1e-5f));
  }
}

// ---------------------------------------------------------------------------
// Kernel 2: hn_t[b][n][c] = bf16((x[b][c][n]-mean)*rstd*w + bias), transposed.
// ---------------------------------------------------------------------------
__global__ __launch_bounds__(256) void gn_apply(const float* __restrict__ x,
                                                const float* __restrict__ nwp,
                                                const float* __restrict__ nbp,
                                                const float2* __restrict__ stats,
                                                bf16* __restrict__ hnt) {
  int b = blockIdx.z, nt = blockIdx.y, ct = blockIdx.x;
  int t = threadIdx.x, w = t >> 6, l = t & 63;
  int wc = w & 1, wn = w >> 1;
  int cb = ct * 128 + wc * 64 + (l & 7) * 8;   // 8 channels per lane
  int n0 = nt * 64 + wn * 32 + (l >> 3) * 4;   // 4 n per lane
  float2 ms = stats[b * 32 + (cb >> 4)];
  float wgt[8], bia[8];
#pragma unroll
  for (int i = 0; i < 8; i++) {
    float wi = nwp[cb + i] * ms.y;
    wgt[i] = wi;
    bia[i] = nbp[cb + i] - ms.x * wi;
  }
  F4 in[8];
  const float* xb = x + ((size_t)b * 512 + cb) * 1024 + n0;
#pragma unroll
  for (int i = 0; i < 8; i++) in[i].v = *(const float4*)(xb + (size_t)i * 1024);
  bf16* ob = hnt + ((size_t)b * 1024 + n0) * 512 + cb;
#pragma unroll
  for (int j = 0; j < 4; j++) {
    U8 o;
#pragma unroll
    for (int i = 0; i < 8; i++) o.h[i] = (bf16)(in[i].f[j] * wgt[i] + bia[i]);
    *(uint4*)(ob + (size_t)j * 512) = o.u4;
  }
}

// ---------------------------------------------------------------------------
// Shared gemm-BT core (m97 recipe).
// ---------------------------------------------------------------------------
__device__ __forceinline__ void gemm_bt_core(const bf16* ga0, const bf16* gb0,
                                             bf16* At, bf16* Bt,
                                             f32x4 (&acc)[4][4], int w, int l) {
  const bf16* ga = ga0 + (size_t)(w * 16 + (l >> 2)) * 512 + (l & 3) * 8;
  const bf16* gb = gb0 + (size_t)(w * 16 + (l >> 2)) * 512 + (l & 3) * 8;
  int wr = w >> 1, wc = w & 1;
  const bf16* Ab = At + (wr * 64 + (l & 15)) * 32 + (l >> 4) * 8;
  const bf16* Bb = Bt + (wc * 64 + (l & 15)) * 32 + (l >> 4) * 8;
  bf16* lA = At + w * 16 * 32;
  bf16* lB = Bt + w * 16 * 32;
  for (int k0 = 0; k0 < 512; k0 += 32) {
    async16(ga + k0, lA);
    async16(ga + 64 * 512 + k0, lA + 64 * 32);
    async16(gb + k0, lB);
    async16(gb + 64 * 512 + k0, lB + 64 * 32);
    __syncthreads();
    bf16x8 af[4], bfr[4];
#pragma unroll
    for (int i = 0; i < 4; i++) {
      af[i] = *(const bf16x8*)(Ab + i * 512);
      bfr[i] = *(const bf16x8*)(Bb + i * 512);
    }
#pragma unroll
    for (int i = 0; i < 4; i++)
#pragma unroll
      for (int j = 0; j < 4; j++)
        acc[i][j] = __builtin_amdgcn_mfma_f32_16x16x32_bf16(af[i], bfr[j], acc[i][j], 0, 0, 0);
    __syncthreads();
  }
}

// ---------------------------------------------------------------------------
// Kernel 3: qkv projection GEMM.  Grid (ot=12, nt=8, b=16).
// ---------------------------------------------------------------------------
__global__ __launch_bounds__(256, 2) void qkv_gemm(const bf16* __restrict__ hnt,
                                                   const bf16* __restrict__ qwb,
                                                   const float* __restrict__ qb,
                                                   bf16* __restrict__ qkt,
                                                   bf16* __restrict__ vt) {
  __shared__ bf16 At[128 * 32];
  __shared__ bf16 Bt[128 * 32];
  int b = blockIdx.z, mt = blockIdx.y, ot = blockIdx.x;
  int m0 = mt * 128, o0 = ot * 128;
  int t = threadIdx.x, w = t >> 6, l = t & 63;
  f32x4 acc[4][4] = {};
  gemm_bt_core(hnt + ((size_t)b * 1024 + m0) * 512, qwb + (size_t)o0 * 512, At, Bt, acc, w, l);

  int wr = w >> 1, wc = w & 1, quad = l >> 4, li = l & 15;
#pragma unroll
  for (int i = 0; i < 4; i++) {
    int gn = m0 + wr * 64 + i * 16 + quad * 4;
#pragma unroll
    for (int j = 0; j < 4; j++) {
      int go = o0 + wc * 64 + j * 16 + li;
      float bias = qb[go];
      if (ot < 8) {             // q,k region: (n, o) layout
        bf16* p = qkt + ((size_t)b * 1024 + gn) * 1024 + go;
#pragma unroll
        for (int r = 0; r < 4; r++) p[(size_t)r * 1024] = (bf16)(acc[i][j][r] + bias);
      } else {                  // v region: transposed (d, n), 8B stores
        U4 pk;
#pragma unroll
        for (int r = 0; r < 4; r++) pk.h[r] = (bf16)(acc[i][j][r] + bias);
        *(ushort4*)(vt + ((size_t)b * 512 + (go - 1024)) * 1024 + gn) = pk.u;
      }
    }
  }
}

// ---------------------------------------------------------------------------
// Kernel 4: flash attention, S^T formulation.
// Block = (b, h, 128 q); 4 waves x 32 q each. Per K-tile (128):
//   S^T = K * Q^T  (swapped MFMA operands; C-layout: q = lane&15, k = quad*4+r)
//   -> softmax reduction over k is in-lane + 2 shuffles (xor16, xor32)
//   -> P^T per lane is k-contiguous: 16x ds_write_b64 (xor-swizzled)
//   O^T = V^T * P^T; V^T frags are A-operand (16B global loads, L2-resident).
// No __syncthreads anywhere (per-wave private LDS region).
// ---------------------------------------------------------------------------
__global__ __launch_bounds__(256, 3) void attn(const bf16* __restrict__ qkt,
                                               const bf16* __restrict__ vt,
                                               bf16* __restrict__ ont) {
  __shared__ __align__(16) bf16 plds[4][32 * 136];  // per-wave P^T [q][k], stride 136
  int b = blockIdx.z, h = blockIdx.y, qt = blockIdx.x;
  int t = threadIdx.x, w = t >> 6, l = t & 63;
  int quad = l >> 4, li = l & 15;
  int q0 = qt * 128 + w * 32;
  int sw = (li & 3) << 5;                      // xor swizzle for LDS k-offsets

  const bf16* qb = qkt + (size_t)b * 1048576 + h * 64;
  const bf16* kb = qb + 512;
  const bf16* vb = vt + ((size_t)b * 512 + h * 64) * 1024;

  // Q fragments (B-operand): lane holds Q[q=qf*16+li][d=ks*32+quad*8+j], x0.125
  bf16x8 qfr[2][2];
#pragma unroll
  for (int qf = 0; qf < 2; qf++)
#pragma unroll
    for (int ks = 0; ks < 2; ks++) {
      U8 u;
      u.u4 = *(const uint4*)(qb + (size_t)(q0 + qf * 16 + li) * 1024 + ks * 32 + quad * 8);
#pragma unroll
      for (int i = 0; i < 8; i++) u.h[i] = (bf16)((float)u.h[i] * 0.125f);
      qfr[qf][ks] = u.v;
    }

  float mrun[2] = {-INFINITY, -INFINITY}, lrun[2] = {0.f, 0.f};
  f32x4 of[4][2] = {};                         // O^T accum: [df][qf]
  bf16* pl = plds[w];

  for (int m0 = 0; m0 < 1024; m0 += 128) {
    // ---- S^T = K Q^T : st[qf][kf], k = m0 + kf*16 + quad*4 + r, q = qf*16+li
    f32x4 st[2][8] = {};
#pragma unroll
    for (int kf = 0; kf < 8; kf++) {
      U8 k0, k1;
      const bf16* kr = kb + (size_t)(m0 + kf * 16 + li) * 1024 + quad * 8;
      k0.u4 = *(const uint4*)kr;
      k1.u4 = *(const uint4*)(kr + 32);
#pragma unroll
      for (int qf = 0; qf < 2; qf++)
        st[qf][kf] = __builtin_amdgcn_mfma_f32_16x16x32_bf16(k0.v, qfr[qf][0], st[qf][kf], 0, 0, 0);
#pragma unroll
      for (int qf = 0; qf < 2; qf++)
        st[qf][kf] = __builtin_amdgcn_mfma_f32_16x16x32_bf16(k1.v, qfr[qf][1], st[qf][kf], 0, 0, 0);
    }
    // ---- prefetch V frags for ms=0 (hide latency under softmax) ----
    U8 vf[4];
#pragma unroll
    for (int df = 0; df < 4; df++)
      vf[df].u4 = *(const uint4*)(vb + (size_t)(df * 16 + li) * 1024 + m0 + quad * 8);
    // ---- online softmax over k (in-lane + xor16/xor32) ----
#pragma unroll
    for (int qf = 0; qf < 2; qf++) {
      f32x4 vm = st[qf][0];
#pragma unroll
      for (int kf = 1; kf < 8; kf++)
#pragma unroll
        for (int r = 0; r < 4; r++) vm[r] = fmaxf(vm[r], st[qf][kf][r]);
      float mt = fmaxf(fmaxf(vm[0], vm[1]), fmaxf(vm[2], vm[3]));
      mt = fmaxf(mt, __shfl_xor(mt, 16));
      mt = fmaxf(mt, __shfl_xor(mt, 32));
      float mnew = fmaxf(mrun[qf], mt);
      float alpha = __builtin_amdgcn_exp2f((mrun[qf] - mnew) * LOG2E);
      mrun[qf] = mnew;
      f32x4 vs = {};
#pragma unroll
      for (int kf = 0; kf < 8; kf++) {
        U4 pk;
#pragma unroll
        for (int r = 0; r < 4; r++) {
          float e = __builtin_amdgcn_exp2f((st[qf][kf][r] - mnew) * LOG2E);
          vs[r] += e;
          pk.h[r] = (bf16)e;
        }
        *(ushort4*)(pl + (qf * 16 + li) * 136 + ((kf * 16 + quad * 4) ^ sw)) = pk.u;
      }
      float ls = (vs[0] + vs[1]) + (vs[2] + vs[3]);
      ls += __shfl_xor(ls, 16);
      ls += __shfl_xor(ls, 32);
      lrun[qf] = lrun[qf] * alpha + ls;
#pragma unroll
      for (int df = 0; df < 4; df++)
#pragma unroll
        for (int r = 0; r < 4; r++) of[df][qf][r] *= alpha;
    }
    // ---- O^T += V^T P^T ----
#pragma unroll
    for (int ms = 0; ms < 4; ms++) {
      bf16x8 pfr[2];
#pragma unroll
      for (int qf = 0; qf < 2; qf++)
        pfr[qf] = *(const bf16x8*)(pl + (qf * 16 + li) * 136 + ((ms * 32 + quad * 8) ^ sw));
      U8 vn[4];
      if (ms < 3) {
#pragma unroll
        for (int df = 0; df < 4; df++)
          vn[df].u4 = *(const uint4*)(vb + (size_t)(df * 16 + li) * 1024 + m0 + (ms + 1) * 32 + quad * 8);
      }
#pragma unroll
      for (int df = 0; df < 4; df++)
#pragma unroll
        for (int qf = 0; qf < 2; qf++)
          of[df][qf] = __builtin_amdgcn_mfma_f32_16x16x32_bf16(vf[df].v, pfr[qf], of[df][qf], 0, 0, 0);
#pragma unroll
      for (int df = 0; df < 4; df++) vf[df] = vn[df];
    }
  }
  // ---- epilogue: O[q][d] = O^T/l, packed 8B stores ----
#pragma unroll
  for (int qf = 0; qf < 2; qf++) {
    float inv = 1.f / lrun[qf];
    bf16* ob = ont + ((size_t)b * 1024 + q0 + qf * 16 + li) * 512 + h * 64 + quad * 4;
#pragma unroll
    for (int df = 0; df < 4; df++) {
      U4 pk;
#pragma unroll
      for (int r = 0; r < 4; r++) pk.h[r] = (bf16)(of[df][qf][r] * inv);
      *(ushort4*)(ob + df * 16) = pk.u;
    }
  }
}

// ---------------------------------------------------------------------------
// Kernel 5: proj GEMM + residual. Grid (4, 8, 16).
// ---------------------------------------------------------------------------
__global__ __launch_bounds__(256, 2) void proj_gemm(const bf16* __restrict__ ont,
                                                    const bf16* __restrict__ pwb,
                                                    const float* __restrict__ pb,
                                                    const float* __restrict__ x,
                                                    float* __restrict__ out) {
  __shared__ bf16 At[128 * 32];
  __shared__ bf16 Bt[128 * 32];
  int b = blockIdx.z, mt = blockIdx.y, ot = blockIdx.x;
  int m0 = mt * 128, o0 = ot * 128;
  int t = threadIdx.x, w = t >> 6, l = t & 63;
  f32x4 acc[4][4] = {};
  gemm_bt_core(ont + ((size_t)b * 1024 + m0) * 512, pwb + (size_t)o0 * 512, At, Bt, acc, w, l);

  int wr = w >> 1, wc = w & 1, quad = l >> 4, li = l & 15;
#pragma unroll
  for (int i = 0; i < 4; i++) {
    int gn = m0 + wr * 64 + i * 16 + quad * 4;
#pragma unroll
    for (int j = 0; j < 4; j++) {
      int go = o0 + wc * 64 + j * 16 + li;
      float bias = pb[go];
      F4 xres; xres.v = *(const float4*)(x + ((size_t)b * 512 + go) * 1024 + gn);
      F4 o;
#pragma unroll
      for (int r = 0; r < 4; r++) o.f[r] = acc[i][j][r] + bias + xres.f[r];
      *(float4*)(out + ((size_t)b * 512 + go) * 1024 + gn) = o.v;
    }
  }
}

// ---------------------------------------------------------------------------
extern "C" void kernel_launch(void* const* d_in, const int* in_sizes, int n_in,
                              void* d_out, int out_size, void* d_ws, size_t ws_size,
                              hipStream_t stream) {
  const float* x  = (const float*)d_in[0];
  const float* nw = (const float*)d_in[1];
  const float* nb = (const float*)d_in[2];
  const float* qw = (const float*)d_in[3];
  const float* qb = (const float*)d_in[4];
  const float* pw = (const float*)d_in[5];
  const float* pb = (const float*)d_in[6];
  float* out = (float*)d_out;

  char* ws = (char*)d_ws;
  float2* stats = (float2*)ws;
  bf16* qwb = (bf16*)(ws + (64u << 10));
  bf16* pwb = (bf16*)(ws + (2u << 20));
  bf16* hnt = (bf16*)(ws + (4u << 20));   // reused as ont after qkv_gemm
  bf16* qkt = (bf16*)(ws + (20u << 20));
  bf16* vt  = (bf16*)(ws + (52u << 20));
  bf16* ont = hnt;

  cvt_w<<<1024, 256, 0, stream>>>(qw, pw, qwb, pwb);
  gn_stats<<<512, 256, 0, stream>>>(x, stats);
  gn_apply<<<dim3(4, 16, 16), 256, 0, stream>>>(x, nw, nb, stats, hnt);
  qkv_gemm<<<dim3(12, 8, 16), 256, 0, stream>>>(hnt, qwb, qb, qkt, vt);
  attn<<<dim3(8, 8, 16), 256, 0, stream>>>(qkt, vt, ont);
  proj_gemm<<<dim3(4, 8, 16), 256, 0, stream>>>(ont, pwb, pb, x, out);
}